// Round 1
// baseline (228.928 us; speedup 1.0000x reference)
//
#include <hip/hip_runtime.h>
#include <hip/hip_bf16.h>

// FISM forward, MI355X.
// Shapes (fixed by reference): B=16384, K=50, T=B*K, NNEG=20, D=128.
// One 64-lane wave per batch row; lane owns dims [2*lane, 2*lane+1] (float2).
// All gathers are 512 B/wave coalesced row reads; 21 dot products reduced via
// __shfl_down. Tables (51.2 MB each) fit in L3 -> L2/L3-BW bound.

constexpr int B_SZ  = 16384;
constexpr int K_NB  = 50;
constexpr int NNEG  = 20;
constexpr int D_DIM = 128;

__global__ __launch_bounds__(256) void fism_fwd(
    const int* __restrict__ I,        // [B]
    const int* __restrict__ U,        // [B]
    const int* __restrict__ I_neg,    // [B, NNEG]
    const int* __restrict__ I_U,      // [T]
    const int* __restrict__ N_U,      // [B]
    const int* __restrict__ I_in_I_U, // [B]
    const float* __restrict__ P,      // [N_ITEMS, D]
    const float* __restrict__ Q,      // [N_ITEMS, D]
    const float* __restrict__ b_u,    // [N_USERS]
    const float* __restrict__ b_i,    // [N_ITEMS]
    float* __restrict__ r,            // [B]
    float* __restrict__ r_neg)        // [B, NNEG]
{
    const int wave = (blockIdx.x * blockDim.x + threadIdx.x) >> 6;
    const int lane = threadIdx.x & 63;
    if (wave >= B_SZ) return;
    const int b = wave;

    // ---- sum 50 neighbor P rows ----
    float2 psum = {0.f, 0.f};
    const int base = b * K_NB;
    #pragma unroll 5
    for (int k = 0; k < K_NB; ++k) {
        const int item = I_U[base + k];            // wave-uniform load (broadcast)
        const float2 v = ((const float2*)(P + (size_t)item * D_DIM))[lane];
        psum.x += v.x;
        psum.y += v.y;
    }

    // ---- exclude self, normalize ----
    const int   ii  = I[b];
    const float ind = (float)I_in_I_U[b];
    const float2 ps = ((const float2*)(P + (size_t)ii * D_DIM))[lane];
    const float div = fmaxf((float)N_U[b] - ind, 1.0f);   // ALPHA = 1
    const float inv = 1.0f / div;
    float2 pctx;
    pctx.x = (psum.x - ps.x * ind) * inv;
    pctx.y = (psum.y - ps.y * ind) * inv;

    const float bu = b_u[U[b]];

    // ---- positive dot ----
    {
        const float2 qv = ((const float2*)(Q + (size_t)ii * D_DIM))[lane];
        float dot = pctx.x * qv.x + pctx.y * qv.y;
        #pragma unroll
        for (int off = 32; off > 0; off >>= 1)
            dot += __shfl_down(dot, off, 64);
        if (lane == 0) r[b] = bu + b_i[ii] + dot;
    }

    // ---- 20 negative dots ----
    #pragma unroll 4
    for (int n = 0; n < NNEG; ++n) {
        const int ineg = I_neg[b * NNEG + n];
        const float2 qv = ((const float2*)(Q + (size_t)ineg * D_DIM))[lane];
        float dot = pctx.x * qv.x + pctx.y * qv.y;
        #pragma unroll
        for (int off = 32; off > 0; off >>= 1)
            dot += __shfl_down(dot, off, 64);
        if (lane == 0) r_neg[b * NNEG + n] = bu + b_i[ineg] + dot;
    }
}

extern "C" void kernel_launch(void* const* d_in, const int* in_sizes, int n_in,
                              void* d_out, int out_size, void* d_ws, size_t ws_size,
                              hipStream_t stream) {
    const int*   I        = (const int*)d_in[0];
    const int*   U        = (const int*)d_in[1];
    const int*   I_neg    = (const int*)d_in[2];
    const int*   I_U      = (const int*)d_in[3];
    const int*   N_U      = (const int*)d_in[4];
    const int*   I_in_I_U = (const int*)d_in[5];
    const float* P_emb    = (const float*)d_in[6];
    const float* Q_emb    = (const float*)d_in[7];
    const float* b_u      = (const float*)d_in[8];
    const float* b_i      = (const float*)d_in[9];

    float* r     = (float*)d_out;          // [B]
    float* r_neg = (float*)d_out + B_SZ;   // [B, NNEG]

    // 1 wave per row, 4 waves per block -> B/4 blocks
    const int threads = 256;
    const int blocks  = B_SZ / 4;
    fism_fwd<<<blocks, threads, 0, stream>>>(I, U, I_neg, I_U, N_U, I_in_I_U,
                                             P_emb, Q_emb, b_u, b_i, r, r_neg);
}

// Round 2
// 198.330 us; speedup vs baseline: 1.1543x; 1.1543x over previous
//
#include <hip/hip_runtime.h>
#include <hip/hip_bf16.h>

// FISM forward, MI355X — round 2 (latency-bound fix: maximize MLP).
// One 64-lane wave per batch row. Lane layout: sl = lane&31 owns dims
// [4*sl .. 4*sl+3] (float4); half = lane>>5 selects which of 2 rows a
// wave-load fetches (2 embedding rows per load instruction).
// All 50 neighbor indices + 20 negative indices staged via ONE coalesced
// load each, then broadcast with __shfl (ds_bpermute) -- removes 70
// serialized global index-load latencies from the per-wave chain.

constexpr int B_SZ  = 16384;
constexpr int K_NB  = 50;
constexpr int NNEG  = 20;
constexpr int D_DIM = 128;

__global__ __launch_bounds__(256) void fism_fwd(
    const int* __restrict__ I,        // [B]
    const int* __restrict__ U,        // [B]
    const int* __restrict__ I_neg,    // [B, NNEG]
    const int* __restrict__ I_U,      // [T]
    const int* __restrict__ N_U,      // [B]
    const int* __restrict__ I_in_I_U, // [B]
    const float* __restrict__ P,      // [N_ITEMS, D]
    const float* __restrict__ Q,      // [N_ITEMS, D]
    const float* __restrict__ b_u,    // [N_USERS]
    const float* __restrict__ b_i,    // [N_ITEMS]
    float* __restrict__ r,            // [B]
    float* __restrict__ r_neg)        // [B, NNEG]
{
    const int wave = (blockIdx.x * blockDim.x + threadIdx.x) >> 6;
    if (wave >= B_SZ) return;
    const int lane = threadIdx.x & 63;
    const int sl   = lane & 31;   // sub-lane within half-wave
    const int half = lane >> 5;   // 0 or 1
    const int b    = wave;

    // ---- stage indices: one coalesced load per table ----
    int my_nbr = 0, my_neg = 0;
    if (lane < K_NB)  my_nbr = I_U[b * K_NB + lane];
    if (lane < NNEG)  my_neg = I_neg[b * NNEG + lane];
    const int   ii   = I[b];
    const int   uu   = U[b];
    const float ind  = (float)I_in_I_U[b];
    const float nuf  = (float)N_U[b];

    // second-level scalar gathers (issued early; latency hides under P loop)
    const float bu     = b_u[uu];
    const float bi_pos = b_i[ii];
    float my_bneg = 0.f;
    if (lane < NNEG) my_bneg = b_i[my_neg];

    // early row loads: self P row + positive Q row (both halves load the
    // same row -> requests coalesce; each lane gets its 4 dims)
    const float4 ps = ((const float4*)(P + (size_t)ii * D_DIM))[sl];
    const float4 qp = ((const float4*)(Q + (size_t)ii * D_DIM))[sl];

    // ---- P-sum: 2 neighbor rows per wave-load, 25 iterations ----
    float4 acc = {0.f, 0.f, 0.f, 0.f};
    #pragma unroll 5
    for (int k = 0; k < K_NB / 2; ++k) {
        const int item = __shfl(my_nbr, 2 * k + half, 64);
        const float4 v = ((const float4*)(P + (size_t)item * D_DIM))[sl];
        acc.x += v.x; acc.y += v.y; acc.z += v.z; acc.w += v.w;
    }
    // combine even-row half with odd-row half
    acc.x += __shfl_xor(acc.x, 32, 64);
    acc.y += __shfl_xor(acc.y, 32, 64);
    acc.z += __shfl_xor(acc.z, 32, 64);
    acc.w += __shfl_xor(acc.w, 32, 64);

    const float inv = 1.0f / fmaxf(nuf - ind, 1.0f);   // ALPHA = 1
    float4 pctx;
    pctx.x = (acc.x - ps.x * ind) * inv;
    pctx.y = (acc.y - ps.y * ind) * inv;
    pctx.z = (acc.z - ps.z * ind) * inv;
    pctx.w = (acc.w - ps.w * ind) * inv;

    // ---- positive dot (reduce within 32-lane half: 5 shfl steps) ----
    {
        float dot = pctx.x * qp.x + pctx.y * qp.y + pctx.z * qp.z + pctx.w * qp.w;
        #pragma unroll
        for (int m = 16; m > 0; m >>= 1)
            dot += __shfl_xor(dot, m, 64);
        if (lane == 0) r[b] = bu + bi_pos + dot;
    }

    // ---- negatives: 2 per iteration (one per half-wave), 10 iterations ----
    #pragma unroll 5
    for (int t = 0; t < NNEG / 2; ++t) {
        const int   n    = 2 * t + half;
        const int   item = __shfl(my_neg,  n, 64);
        const float bn   = __shfl(my_bneg, n, 64);
        const float4 qv  = ((const float4*)(Q + (size_t)item * D_DIM))[sl];
        float d = pctx.x * qv.x + pctx.y * qv.y + pctx.z * qv.z + pctx.w * qv.w;
        #pragma unroll
        for (int m = 16; m > 0; m >>= 1)
            d += __shfl_xor(d, m, 64);
        if (sl == 0) r_neg[b * NNEG + n] = bu + bn + d;  // lane 0 and lane 32
    }
}

extern "C" void kernel_launch(void* const* d_in, const int* in_sizes, int n_in,
                              void* d_out, int out_size, void* d_ws, size_t ws_size,
                              hipStream_t stream) {
    const int*   I        = (const int*)d_in[0];
    const int*   U        = (const int*)d_in[1];
    const int*   I_neg    = (const int*)d_in[2];
    const int*   I_U      = (const int*)d_in[3];
    const int*   N_U      = (const int*)d_in[4];
    const int*   I_in_I_U = (const int*)d_in[5];
    const float* P_emb    = (const float*)d_in[6];
    const float* Q_emb    = (const float*)d_in[7];
    const float* b_u      = (const float*)d_in[8];
    const float* b_i      = (const float*)d_in[9];

    float* r     = (float*)d_out;          // [B]
    float* r_neg = (float*)d_out + B_SZ;   // [B, NNEG]

    const int threads = 256;               // 4 waves/block, 1 row/wave
    const int blocks  = B_SZ / 4;
    fism_fwd<<<blocks, threads, 0, stream>>>(I, U, I_neg, I_U, N_U, I_in_I_U,
                                             P_emb, Q_emb, b_u, b_i, r, r_neg);
}